// Round 8
// baseline (77.549 us; speedup 1.0000x reference)
//
#include <hip/hip_runtime.h>
#include <hip/hip_bf16.h>

typedef short bf16x8 __attribute__((ext_vector_type(8)));
typedef float f32x4  __attribute__((ext_vector_type(4)));
typedef unsigned short u16;
typedef unsigned long long u64;

// float -> bf16 round-to-nearest-even
static __device__ __forceinline__ u16 f2bf(float f) {
    unsigned u = __float_as_uint(f);
    u += 0x7FFFu + ((u >> 16) & 1u);
    return (u16)(u >> 16);
}
static __device__ __forceinline__ float bf2f(u16 b) {
    return __uint_as_float(((unsigned)b) << 16);
}
static __device__ __forceinline__ unsigned pack2(float lo, float hi) {
    return (unsigned)f2bf(lo) | ((unsigned)f2bf(hi) << 16);
}

// ---------------------------------------------------------------------------
// 8-way edge partition by src range (bucket = s / ceil(M/8)). NO global
// atomics (R6 lesson: global cursor atomics cross-XCD ping-pong = 98us).
// hist: per-block LDS counts -> cnt[k][blk]; scan: one block, bucket-major
// exclusive prefix; scatter: base + LDS-local rank, deterministic.
// ---------------------------------------------------------------------------
#define CH 1024   // edges per partition block

__global__ __launch_bounds__(256) void eb_hist(
    const int* __restrict__ ei, int* __restrict__ cnt,
    int E, int NBLK, int bsz)
{
    __shared__ int h[8];
    int b = blockIdx.x;
    if (threadIdx.x < 8) h[threadIdx.x] = 0;
    __syncthreads();
    int lo = b * CH, hi = min(lo + CH, E);
    for (int e = lo + threadIdx.x; e < hi; e += 256)
        atomicAdd(&h[ei[e] / bsz], 1);
    __syncthreads();
    if (threadIdx.x < 8) cnt[threadIdx.x * NBLK + b] = h[threadIdx.x];
}

__global__ __launch_bounds__(1024) void eb_scan(
    const int* __restrict__ cnt, int* __restrict__ base, int NBLK)
{
    __shared__ int part[1024];
    int n = 8 * NBLK;
    int per = (n + 1023) / 1024;
    int t = threadIdx.x;
    int lo = t * per, hi = min(lo + per, n);
    int sum = 0;
    for (int i = lo; i < hi; ++i) sum += cnt[i];
    part[t] = sum;
    __syncthreads();
    for (int off = 1; off < 1024; off <<= 1) {
        int v = part[t] + ((t >= off) ? part[t - off] : 0);
        __syncthreads();
        part[t] = v;
        __syncthreads();
    }
    int run = (t == 0) ? 0 : part[t - 1];   // exclusive prefix of partials
    for (int i = lo; i < hi; ++i) { base[i] = run; run += cnt[i]; }
}

__global__ __launch_bounds__(256) void eb_scatter(
    const int* __restrict__ ei, const int* __restrict__ base,
    u64* __restrict__ se, int E, int NBLK, int bsz)
{
    __shared__ int h[8];
    __shared__ int bb[8];
    int b = blockIdx.x;
    if (threadIdx.x < 8) {
        h[threadIdx.x]  = 0;
        bb[threadIdx.x] = base[threadIdx.x * NBLK + b];
    }
    __syncthreads();
    int lo = b * CH, hi = min(lo + CH, E);
    for (int e = lo + threadIdx.x; e < hi; e += 256) {
        int s = ei[e], d = ei[E + e];
        int k = s / bsz;
        int pos = bb[k] + atomicAdd(&h[k], 1);     // LDS atomic only
        se[pos] = (u64)(unsigned)s | ((u64)(unsigned)d << 17) | ((u64)e << 34);
    }
}

// ---------------------------------------------------------------------------
// Persistent GEMM (unchanged from R7, 24us, no spill at (256,2)).
// PQ[m][c] = sum_k z[m][k]*W'[c][k] + b1[c] (c<128). bf16 out, fp32 accum.
// ---------------------------------------------------------------------------
#define BM 64
__global__ __launch_bounds__(256, 2) void node_gemm(
    const float* __restrict__ z,   // [M][128] fp32
    const float* __restrict__ W1,  // [256][128] fp32
    const float* __restrict__ b1,  // [128]
    u16*         __restrict__ PQ,  // [M][256] bf16
    int M, int ntiles)
{
    __shared__ char As[BM * 256];
    __shared__ char Cb[BM * 512];
    const int tid  = threadIdx.x;
    const int lane = tid & 63;
    const int wave = tid >> 6;
    const int g    = lane >> 4;
    const int ln   = lane & 15;
    const int c0   = wave * 64;

    int t = blockIdx.x;
    if (t >= ntiles) return;

    bf16x8 af[4][4];
    #pragma unroll
    for (int ci = 0; ci < 4; ++ci) {
        int c = c0 + ci * 16 + ln;
        const float* src = (c < 128) ? (W1 + c) : (W1 + 128 * 128 + (c - 128));
        #pragma unroll
        for (int ks = 0; ks < 4; ++ks) {
            bf16x8 v;
            #pragma unroll
            for (int j = 0; j < 8; ++j)
                v[j] = (short)f2bf(src[(ks * 32 + g * 8 + j) * 128]);
            af[ks][ci] = v;
        }
    }

    float4 bias[4];
    #pragma unroll
    for (int ci = 0; ci < 4; ++ci) {
        int col = c0 + ci * 16 + g * 4;
        bias[ci] = (col < 128) ? *(const float4*)(b1 + col)
                               : make_float4(0.f, 0.f, 0.f, 0.f);
    }

    float4 r[8];
    {
        int m0 = t * BM;
        #pragma unroll
        for (int i = 0; i < 8; ++i) {
            int ci = tid + i * 256, row = ci >> 5, c4 = ci & 31;
            r[i] = make_float4(0.f, 0.f, 0.f, 0.f);
            if (m0 + row < M)
                r[i] = *(const float4*)(z + (size_t)(m0 + row) * 128 + c4 * 4);
        }
        #pragma unroll
        for (int i = 0; i < 8; ++i) {
            int ci = tid + i * 256, row = ci >> 5, c4 = ci & 31;
            ushort4 b;
            b.x = f2bf(r[i].x); b.y = f2bf(r[i].y);
            b.z = f2bf(r[i].z); b.w = f2bf(r[i].w);
            *(ushort4*)(As + row * 256 + ((c4 * 8) ^ ((row & 7) << 4))) = b;
        }
    }
    __syncthreads();

    while (true) {
        int next = t + gridDim.x;
        bool have = (next < ntiles);

        if (have) {
            int m0 = next * BM;
            #pragma unroll
            for (int i = 0; i < 8; ++i) {
                int ci = tid + i * 256, row = ci >> 5, c4 = ci & 31;
                r[i] = make_float4(0.f, 0.f, 0.f, 0.f);
                if (m0 + row < M)
                    r[i] = *(const float4*)(z + (size_t)(m0 + row) * 128 + c4 * 4);
            }
        }

        f32x4 acc[4][4];
        #pragma unroll
        for (int mf = 0; mf < 4; ++mf)
            #pragma unroll
            for (int ci = 0; ci < 4; ++ci)
                acc[mf][ci] = (f32x4){0.f, 0.f, 0.f, 0.f};
        #pragma unroll
        for (int ks = 0; ks < 4; ++ks) {
            #pragma unroll
            for (int mf = 0; mf < 4; ++mf) {
                int row  = mf * 16 + ln;
                int byte = row * 256 + ((ks * 64 + g * 16) ^ ((row & 7) << 4));
                bf16x8 b = *(const bf16x8*)(As + byte);
                #pragma unroll
                for (int ci = 0; ci < 4; ++ci)
                    acc[mf][ci] = __builtin_amdgcn_mfma_f32_16x16x32_bf16(
                        af[ks][ci], b, acc[mf][ci], 0, 0, 0);
            }
        }

        #pragma unroll
        for (int mf = 0; mf < 4; ++mf) {
            int node = mf * 16 + ln;
            #pragma unroll
            for (int ci = 0; ci < 4; ++ci) {
                int col = c0 + ci * 16 + g * 4;
                uint2 w;
                w.x = pack2(acc[mf][ci][0] + bias[ci].x,
                            acc[mf][ci][1] + bias[ci].y);
                w.y = pack2(acc[mf][ci][2] + bias[ci].z,
                            acc[mf][ci][3] + bias[ci].w);
                *(uint2*)(Cb + node * 512 + ((col * 2) ^ ((node & 7) << 4))) = w;
            }
        }
        __syncthreads();

        {
            int m0 = t * BM;
            int chunk = tid & 31;
            int nb    = tid >> 5;
            #pragma unroll
            for (int it = 0; it < 8; ++it) {
                int node = it * 8 + nb;
                uint4 v = *(const uint4*)(Cb + node * 512 +
                                          ((chunk * 16) ^ ((node & 7) << 4)));
                if (m0 + node < M)
                    *(uint4*)(PQ + (size_t)(m0 + node) * 256 + chunk * 8) = v;
            }
        }

        if (have) {
            #pragma unroll
            for (int i = 0; i < 8; ++i) {
                int ci = tid + i * 256, row = ci >> 5, c4 = ci & 31;
                ushort4 b;
                b.x = f2bf(r[i].x); b.y = f2bf(r[i].y);
                b.z = f2bf(r[i].z); b.w = f2bf(r[i].w);
                *(ushort4*)(As + row * 256 + ((c4 * 8) ^ ((row & 7) << 4))) = b;
            }
        } else {
            break;
        }
        __syncthreads();
        t = next;
    }
}

// ---------------------------------------------------------------------------
// Edge kernel over partitioned edges. 64 edges/block; XCD swizzle gives each
// XCD a contiguous sorted range -> its src bucket (~3.2MB P) stays L2-hot.
// ---------------------------------------------------------------------------
__global__ __launch_bounds__(256) void edge_mlp_sorted(
    const u64* __restrict__ se,    // packed (e<<34)|(d<<17)|s, bucket-ordered
    const u16* __restrict__ PQ,    // [M][256] bf16 (P first 128, Q last 128)
    const float* __restrict__ W2, const float* __restrict__ b2,
    float* __restrict__ out, int E)
{
    int cpx = gridDim.x >> 3;      // gridDim.x is a multiple of 8
    int swz = (blockIdx.x & 7) * cpx + (blockIdx.x >> 3);
    int pos0 = swz * 64 + (threadIdx.x >> 4) * 4;
    int sub  = threadIdx.x & 15;
    if (pos0 >= E) return;

    float4 w2a = *(const float4*)(W2 + sub * 8);
    float4 w2b = *(const float4*)(W2 + sub * 8 + 4);
    float ww[8] = {w2a.x, w2a.y, w2a.z, w2a.w, w2b.x, w2b.y, w2b.z, w2b.w};
    float bias = b2[0];

    if (pos0 + 3 < E) {
        ulonglong2 A = *(const ulonglong2*)(se + pos0);
        ulonglong2 B = *(const ulonglong2*)(se + pos0 + 2);
        u64 v[4] = {A.x, A.y, B.x, B.y};
        float a[4];
        uint4 pv[4], qv[4];
        #pragma unroll
        for (int k = 0; k < 4; ++k) {
            unsigned s = (unsigned)(v[k] & 0x1FFFF);
            unsigned d = (unsigned)((v[k] >> 17) & 0x1FFFF);
            pv[k] = *(const uint4*)(PQ + (size_t)s * 256 + sub * 8);
            qv[k] = *(const uint4*)(PQ + (size_t)d * 256 + 128 + sub * 8);
        }
        #pragma unroll
        for (int k = 0; k < 4; ++k) {
            const u16* pu = (const u16*)&pv[k];
            const u16* qu = (const u16*)&qv[k];
            float acc = 0.f;
            #pragma unroll
            for (int j = 0; j < 8; ++j)
                acc = fmaf(fmaxf(bf2f(pu[j]) + bf2f(qu[j]), 0.f), ww[j], acc);
            a[k] = acc;
        }
        #pragma unroll
        for (int m = 1; m < 16; m <<= 1) {
            a[0] += __shfl_xor(a[0], m);
            a[1] += __shfl_xor(a[1], m);
            a[2] += __shfl_xor(a[2], m);
            a[3] += __shfl_xor(a[3], m);
        }
        if (sub == 0) {
            #pragma unroll
            for (int k = 0; k < 4; ++k)
                out[(unsigned)(v[k] >> 34)] = a[k] + bias;
        }
    } else {
        for (int k = 0; k < 4; ++k) {
            int pos = pos0 + k;
            if (pos >= E) break;
            u64 v = se[pos];
            unsigned s = (unsigned)(v & 0x1FFFF);
            unsigned d = (unsigned)((v >> 17) & 0x1FFFF);
            uint4 p = *(const uint4*)(PQ + (size_t)s * 256 + sub * 8);
            uint4 q = *(const uint4*)(PQ + (size_t)d * 256 + 128 + sub * 8);
            const u16* pu = (const u16*)&p; const u16* qu = (const u16*)&q;
            float acc = 0.f;
            #pragma unroll
            for (int j = 0; j < 8; ++j)
                acc = fmaf(fmaxf(bf2f(pu[j]) + bf2f(qu[j]), 0.f), ww[j], acc);
            #pragma unroll
            for (int m = 1; m < 16; m <<= 1) acc += __shfl_xor(acc, m);
            if (sub == 0) out[(unsigned)(v >> 34)] = acc + bias;
        }
    }
}

// Fallback: unsorted edge kernel (proven 47us).
__global__ __launch_bounds__(256) void edge_mlp(
    const int* __restrict__ ei, const u16* __restrict__ PQ,
    const float* __restrict__ W2, const float* __restrict__ b2,
    float* __restrict__ out, int E)
{
    int gid = blockIdx.x * 256 + threadIdx.x;
    int e0  = (gid >> 4) * 4;
    int sub = gid & 15;
    if (e0 >= E) return;
    float4 w2a = *(const float4*)(W2 + sub * 8);
    float4 w2b = *(const float4*)(W2 + sub * 8 + 4);
    float ww[8] = {w2a.x, w2a.y, w2a.z, w2a.w, w2b.x, w2b.y, w2b.z, w2b.w};
    float bias = b2[0];
    for (int k = 0; k < 4; ++k) {
        int e = e0 + k;
        if (e >= E) break;
        int sn = ei[e], dn = ei[E + e];
        uint4 p = *(const uint4*)(PQ + (size_t)sn * 256 + sub * 8);
        uint4 q = *(const uint4*)(PQ + (size_t)dn * 256 + 128 + sub * 8);
        const u16* pu = (const u16*)&p; const u16* qu = (const u16*)&q;
        float acc = 0.f;
        #pragma unroll
        for (int j = 0; j < 8; ++j)
            acc = fmaf(fmaxf(bf2f(pu[j]) + bf2f(qu[j]), 0.f), ww[j], acc);
        #pragma unroll
        for (int m = 1; m < 16; m <<= 1) acc += __shfl_xor(acc, m);
        if (sub == 0) out[e] = acc + bias;
    }
}

// ---------------------------------------------------------------------------
extern "C" void kernel_launch(void* const* d_in, const int* in_sizes, int n_in,
                              void* d_out, int out_size, void* d_ws, size_t ws_size,
                              hipStream_t stream) {
    const float* z  = (const float*)d_in[0];
    const int*   ei = (const int*)d_in[1];
    const float* W1 = (const float*)d_in[2];
    const float* b1 = (const float*)d_in[3];
    const float* W2 = (const float*)d_in[4];
    const float* b2 = (const float*)d_in[5];
    float* out = (float*)d_out;

    const int M = in_sizes[0] / 128;   // 100000 nodes
    const int E = in_sizes[1] / 2;     // 640000 edges

    char* ws = (char*)d_ws;
    size_t pqBytes = (size_t)M * 256 * 2;          // 51.2 MB
    u16* PQ   = (u16*)ws;
    int* cnt  = (int*)(ws + pqBytes);              // 32 KB
    int* base = (int*)(ws + pqBytes + 32768);      // 32 KB
    u64* se   = (u64*)(ws + pqBytes + 65536);      // E*8 B

    const int NBLK = (E + CH - 1) / CH;
    const int bsz  = (M + 7) / 8;
    size_t need = pqBytes + 65536 + (size_t)E * 8;
    bool do_sort = (ws_size >= need) && (NBLK <= 1024) &&
                   (M < (1 << 17)) && (E <= (1 << 20));

    if (do_sort) {
        hipLaunchKernelGGL(eb_hist, dim3(NBLK), dim3(256), 0, stream,
                           ei, cnt, E, NBLK, bsz);
        hipLaunchKernelGGL(eb_scan, dim3(1), dim3(1024), 0, stream,
                           cnt, base, NBLK);
        hipLaunchKernelGGL(eb_scatter, dim3(NBLK), dim3(256), 0, stream,
                           ei, base, se, E, NBLK, bsz);
    }

    int ntiles = (M + BM - 1) / BM;
    int gb = ntiles < 512 ? ntiles : 512;
    hipLaunchKernelGGL(node_gemm, dim3(gb), dim3(256), 0, stream,
                       z, W1, b1, PQ, M, ntiles);

    if (do_sort) {
        int nwg = (E + 63) / 64;
        nwg = (nwg + 7) & ~7;            // multiple of 8: bijective XCD swizzle
        hipLaunchKernelGGL(edge_mlp_sorted, dim3(nwg), dim3(256), 0, stream,
                           se, PQ, W2, b2, out, E);
    } else {
        int eb = ((E + 3) / 4 * 16 + 255) / 256;
        hipLaunchKernelGGL(edge_mlp, dim3(eb), dim3(256), 0, stream,
                           ei, PQ, W2, b2, out, E);
    }
}

// Round 9
// 76.957 us; speedup vs baseline: 1.0077x; 1.0077x over previous
//
#include <hip/hip_runtime.h>
#include <hip/hip_bf16.h>

typedef short bf16x8 __attribute__((ext_vector_type(8)));
typedef float f32x4  __attribute__((ext_vector_type(4)));
typedef unsigned short u16;
typedef unsigned long long u64;

// float -> bf16 round-to-nearest-even
static __device__ __forceinline__ u16 f2bf(float f) {
    unsigned u = __float_as_uint(f);
    u += 0x7FFFu + ((u >> 16) & 1u);
    return (u16)(u >> 16);
}
static __device__ __forceinline__ float bf2f(u16 b) {
    return __uint_as_float(((unsigned)b) << 16);
}
static __device__ __forceinline__ unsigned pack2(float lo, float hi) {
    return (unsigned)f2bf(lo) | ((unsigned)f2bf(hi) << 16);
}

// ---------------------------------------------------------------------------
// Persistent GEMM (R7-proven, ~24us, no spill at (256,2)).
// PQ[m][c] = sum_k z[m][k]*W'[c][k] + b1[c] (c<128). bf16 out, fp32 accum.
// ---------------------------------------------------------------------------
#define BM 64
__global__ __launch_bounds__(256, 2) void node_gemm(
    const float* __restrict__ z,   // [M][128] fp32
    const float* __restrict__ W1,  // [256][128] fp32
    const float* __restrict__ b1,  // [128]
    u16*         __restrict__ PQ,  // [M][256] bf16
    int M, int ntiles)
{
    __shared__ char As[BM * 256];
    __shared__ char Cb[BM * 512];
    const int tid  = threadIdx.x;
    const int lane = tid & 63;
    const int wave = tid >> 6;
    const int g    = lane >> 4;
    const int ln   = lane & 15;
    const int c0   = wave * 64;

    int t = blockIdx.x;
    if (t >= ntiles) return;

    bf16x8 af[4][4];
    #pragma unroll
    for (int ci = 0; ci < 4; ++ci) {
        int c = c0 + ci * 16 + ln;
        const float* src = (c < 128) ? (W1 + c) : (W1 + 128 * 128 + (c - 128));
        #pragma unroll
        for (int ks = 0; ks < 4; ++ks) {
            bf16x8 v;
            #pragma unroll
            for (int j = 0; j < 8; ++j)
                v[j] = (short)f2bf(src[(ks * 32 + g * 8 + j) * 128]);
            af[ks][ci] = v;
        }
    }

    float4 bias[4];
    #pragma unroll
    for (int ci = 0; ci < 4; ++ci) {
        int col = c0 + ci * 16 + g * 4;
        bias[ci] = (col < 128) ? *(const float4*)(b1 + col)
                               : make_float4(0.f, 0.f, 0.f, 0.f);
    }

    float4 r[8];
    {
        int m0 = t * BM;
        #pragma unroll
        for (int i = 0; i < 8; ++i) {
            int ci = tid + i * 256, row = ci >> 5, c4 = ci & 31;
            r[i] = make_float4(0.f, 0.f, 0.f, 0.f);
            if (m0 + row < M)
                r[i] = *(const float4*)(z + (size_t)(m0 + row) * 128 + c4 * 4);
        }
        #pragma unroll
        for (int i = 0; i < 8; ++i) {
            int ci = tid + i * 256, row = ci >> 5, c4 = ci & 31;
            ushort4 b;
            b.x = f2bf(r[i].x); b.y = f2bf(r[i].y);
            b.z = f2bf(r[i].z); b.w = f2bf(r[i].w);
            *(ushort4*)(As + row * 256 + ((c4 * 8) ^ ((row & 7) << 4))) = b;
        }
    }
    __syncthreads();

    while (true) {
        int next = t + gridDim.x;
        bool have = (next < ntiles);

        if (have) {
            int m0 = next * BM;
            #pragma unroll
            for (int i = 0; i < 8; ++i) {
                int ci = tid + i * 256, row = ci >> 5, c4 = ci & 31;
                r[i] = make_float4(0.f, 0.f, 0.f, 0.f);
                if (m0 + row < M)
                    r[i] = *(const float4*)(z + (size_t)(m0 + row) * 128 + c4 * 4);
            }
        }

        f32x4 acc[4][4];
        #pragma unroll
        for (int mf = 0; mf < 4; ++mf)
            #pragma unroll
            for (int ci = 0; ci < 4; ++ci)
                acc[mf][ci] = (f32x4){0.f, 0.f, 0.f, 0.f};
        #pragma unroll
        for (int ks = 0; ks < 4; ++ks) {
            #pragma unroll
            for (int mf = 0; mf < 4; ++mf) {
                int row  = mf * 16 + ln;
                int byte = row * 256 + ((ks * 64 + g * 16) ^ ((row & 7) << 4));
                bf16x8 b = *(const bf16x8*)(As + byte);
                #pragma unroll
                for (int ci = 0; ci < 4; ++ci)
                    acc[mf][ci] = __builtin_amdgcn_mfma_f32_16x16x32_bf16(
                        af[ks][ci], b, acc[mf][ci], 0, 0, 0);
            }
        }

        #pragma unroll
        for (int mf = 0; mf < 4; ++mf) {
            int node = mf * 16 + ln;
            #pragma unroll
            for (int ci = 0; ci < 4; ++ci) {
                int col = c0 + ci * 16 + g * 4;
                uint2 w;
                w.x = pack2(acc[mf][ci][0] + bias[ci].x,
                            acc[mf][ci][1] + bias[ci].y);
                w.y = pack2(acc[mf][ci][2] + bias[ci].z,
                            acc[mf][ci][3] + bias[ci].w);
                *(uint2*)(Cb + node * 512 + ((col * 2) ^ ((node & 7) << 4))) = w;
            }
        }
        __syncthreads();

        {
            int m0 = t * BM;
            int chunk = tid & 31;
            int nb    = tid >> 5;
            #pragma unroll
            for (int it = 0; it < 8; ++it) {
                int node = it * 8 + nb;
                uint4 v = *(const uint4*)(Cb + node * 512 +
                                          ((chunk * 16) ^ ((node & 7) << 4)));
                if (m0 + node < M)
                    *(uint4*)(PQ + (size_t)(m0 + node) * 256 + chunk * 8) = v;
            }
        }

        if (have) {
            #pragma unroll
            for (int i = 0; i < 8; ++i) {
                int ci = tid + i * 256, row = ci >> 5, c4 = ci & 31;
                ushort4 b;
                b.x = f2bf(r[i].x); b.y = f2bf(r[i].y);
                b.z = f2bf(r[i].z); b.w = f2bf(r[i].w);
                *(ushort4*)(As + row * 256 + ((c4 * 8) ^ ((row & 7) << 4))) = b;
            }
        } else {
            break;
        }
        __syncthreads();
        t = next;
    }
}

// ---------------------------------------------------------------------------
// Own-compute filtered edge kernel. Block b: bucket = b&7 (rides blockIdx%8 ->
// XCD round-robin), chunk = b>>3. Streams its 2048-edge chunk, ballot-compacts
// edges whose src is in the bucket's node range into an LDS queue (NO global
// atomics - R6 lesson), then processes with the 4-edge-ILP gather path.
// P gathers confined to the XCD's ~3.2MB range -> L2-hot (R8's proven win),
// without R8's ~15us of sort kernels. Q stays random (irreducible).
// ---------------------------------------------------------------------------
#define FCH 2048   // edges per chunk
__global__ __launch_bounds__(256) void edge_mlp_filter(
    const int* __restrict__ ei,    // [2][E] int32
    const u16* __restrict__ PQ,    // [M][256] bf16 (P first 128, Q last 128)
    const float* __restrict__ W2,  // [128]
    const float* __restrict__ b2,  // [1]
    float* __restrict__ out,       // [E]
    int E, int M)
{
    __shared__ u64 q[512];
    __shared__ int qn;
    __shared__ int pn;   // snapshot of queue size for process phase

    const int tid  = threadIdx.x;
    const int myb  = blockIdx.x & 7;
    const int chnk = blockIdx.x >> 3;
    const int bsz  = (M + 7) >> 3;
    const int lo   = myb * bsz;
    const int hi   = (lo + bsz < M) ? (lo + bsz) : M;
    const int sub  = tid & 15;
    const int grp  = tid >> 4;     // 16 groups of 16 lanes

    float4 w2a = *(const float4*)(W2 + sub * 8);
    float4 w2b = *(const float4*)(W2 + sub * 8 + 4);
    float ww[8] = {w2a.x, w2a.y, w2a.z, w2a.w, w2b.x, w2b.y, w2b.z, w2b.w};
    float bias = b2[0];

    if (tid == 0) qn = 0;
    __syncthreads();

    const int e0 = chnk * FCH;
    #pragma unroll 1
    for (int r = 0; r < FCH / 256; ++r) {
        // ---- filter 256 edges into the queue ----
        int e = e0 + r * 256 + tid;
        int s = 0, d = 0;
        bool mine = false;
        if (e < E) {
            s = ei[e];
            if (s >= lo && s < hi) { mine = true; d = ei[E + e]; }
        }
        u64 mask = __ballot(mine);
        int rank = __popcll(mask & ((1ULL << (tid & 63)) - 1ULL));
        int wcnt = __popcll(mask);
        int wb = 0;
        if ((tid & 63) == 0 && wcnt) wb = atomicAdd(&qn, wcnt);
        wb = __shfl(wb, 0);
        if (mine)
            q[wb + rank] = (u64)(unsigned)s | ((u64)(unsigned)d << 17)
                         | ((u64)(unsigned)e << 34);
        __syncthreads();

        // ---- process when queue may overflow next round, or at the end ----
        bool flush = (qn > 256) || (r == FCH / 256 - 1);
        if (flush) {
            if (tid == 0) { pn = qn; qn = 0; }
            __syncthreads();
            int n = pn;
            for (int base = grp * 4; base < n; base += 64) {
                if (base + 4 <= n) {
                    u64 v0 = q[base], v1 = q[base + 1];
                    u64 v2 = q[base + 2], v3 = q[base + 3];
                    unsigned s0 = (unsigned)(v0 & 0x1FFFF), d0 = (unsigned)((v0 >> 17) & 0x1FFFF);
                    unsigned s1 = (unsigned)(v1 & 0x1FFFF), d1 = (unsigned)((v1 >> 17) & 0x1FFFF);
                    unsigned s2 = (unsigned)(v2 & 0x1FFFF), d2 = (unsigned)((v2 >> 17) & 0x1FFFF);
                    unsigned s3 = (unsigned)(v3 & 0x1FFFF), d3 = (unsigned)((v3 >> 17) & 0x1FFFF);
                    uint4 p0 = *(const uint4*)(PQ + (size_t)s0 * 256 + sub * 8);
                    uint4 p1 = *(const uint4*)(PQ + (size_t)s1 * 256 + sub * 8);
                    uint4 p2 = *(const uint4*)(PQ + (size_t)s2 * 256 + sub * 8);
                    uint4 p3 = *(const uint4*)(PQ + (size_t)s3 * 256 + sub * 8);
                    uint4 q0 = *(const uint4*)(PQ + (size_t)d0 * 256 + 128 + sub * 8);
                    uint4 q1 = *(const uint4*)(PQ + (size_t)d1 * 256 + 128 + sub * 8);
                    uint4 q2 = *(const uint4*)(PQ + (size_t)d2 * 256 + 128 + sub * 8);
                    uint4 q3 = *(const uint4*)(PQ + (size_t)d3 * 256 + 128 + sub * 8);
                    float a0 = 0.f, a1 = 0.f, a2 = 0.f, a3 = 0.f;
                    const u16* pu0 = (const u16*)&p0; const u16* qu0 = (const u16*)&q0;
                    const u16* pu1 = (const u16*)&p1; const u16* qu1 = (const u16*)&q1;
                    const u16* pu2 = (const u16*)&p2; const u16* qu2 = (const u16*)&q2;
                    const u16* pu3 = (const u16*)&p3; const u16* qu3 = (const u16*)&q3;
                    #pragma unroll
                    for (int j = 0; j < 8; ++j) {
                        a0 = fmaf(fmaxf(bf2f(pu0[j]) + bf2f(qu0[j]), 0.f), ww[j], a0);
                        a1 = fmaf(fmaxf(bf2f(pu1[j]) + bf2f(qu1[j]), 0.f), ww[j], a1);
                        a2 = fmaf(fmaxf(bf2f(pu2[j]) + bf2f(qu2[j]), 0.f), ww[j], a2);
                        a3 = fmaf(fmaxf(bf2f(pu3[j]) + bf2f(qu3[j]), 0.f), ww[j], a3);
                    }
                    #pragma unroll
                    for (int m = 1; m < 16; m <<= 1) {
                        a0 += __shfl_xor(a0, m);
                        a1 += __shfl_xor(a1, m);
                        a2 += __shfl_xor(a2, m);
                        a3 += __shfl_xor(a3, m);
                    }
                    if (sub == 0) {
                        out[(unsigned)(v0 >> 34)] = a0 + bias;
                        out[(unsigned)(v1 >> 34)] = a1 + bias;
                        out[(unsigned)(v2 >> 34)] = a2 + bias;
                        out[(unsigned)(v3 >> 34)] = a3 + bias;
                    }
                } else {
                    for (int i = base; i < n; ++i) {
                        u64 v = q[i];
                        unsigned s_ = (unsigned)(v & 0x1FFFF);
                        unsigned d_ = (unsigned)((v >> 17) & 0x1FFFF);
                        uint4 p = *(const uint4*)(PQ + (size_t)s_ * 256 + sub * 8);
                        uint4 qq = *(const uint4*)(PQ + (size_t)d_ * 256 + 128 + sub * 8);
                        const u16* pu = (const u16*)&p; const u16* qu = (const u16*)&qq;
                        float acc = 0.f;
                        #pragma unroll
                        for (int j = 0; j < 8; ++j)
                            acc = fmaf(fmaxf(bf2f(pu[j]) + bf2f(qu[j]), 0.f), ww[j], acc);
                        #pragma unroll
                        for (int m = 1; m < 16; m <<= 1) acc += __shfl_xor(acc, m);
                        if (sub == 0) out[(unsigned)(v >> 34)] = acc + bias;
                    }
                }
            }
            __syncthreads();   // queue fully consumed before next fill
        }
    }
}

// Fallback for out-of-range M/E: proven flat edge kernel (47us).
__global__ __launch_bounds__(256) void edge_mlp(
    const int* __restrict__ ei, const u16* __restrict__ PQ,
    const float* __restrict__ W2, const float* __restrict__ b2,
    float* __restrict__ out, int E)
{
    int gid = blockIdx.x * 256 + threadIdx.x;
    int e0  = (gid >> 4) * 4;
    int sub = gid & 15;
    if (e0 >= E) return;
    float4 w2a = *(const float4*)(W2 + sub * 8);
    float4 w2b = *(const float4*)(W2 + sub * 8 + 4);
    float ww[8] = {w2a.x, w2a.y, w2a.z, w2a.w, w2b.x, w2b.y, w2b.z, w2b.w};
    float bias = b2[0];
    for (int k = 0; k < 4; ++k) {
        int e = e0 + k;
        if (e >= E) break;
        int sn = ei[e], dn = ei[E + e];
        uint4 p = *(const uint4*)(PQ + (size_t)sn * 256 + sub * 8);
        uint4 q = *(const uint4*)(PQ + (size_t)dn * 256 + 128 + sub * 8);
        const u16* pu = (const u16*)&p; const u16* qu = (const u16*)&q;
        float acc = 0.f;
        #pragma unroll
        for (int j = 0; j < 8; ++j)
            acc = fmaf(fmaxf(bf2f(pu[j]) + bf2f(qu[j]), 0.f), ww[j], acc);
        #pragma unroll
        for (int m = 1; m < 16; m <<= 1) acc += __shfl_xor(acc, m);
        if (sub == 0) out[e] = acc + bias;
    }
}

// ---------------------------------------------------------------------------
extern "C" void kernel_launch(void* const* d_in, const int* in_sizes, int n_in,
                              void* d_out, int out_size, void* d_ws, size_t ws_size,
                              hipStream_t stream) {
    const float* z  = (const float*)d_in[0];
    const int*   ei = (const int*)d_in[1];
    const float* W1 = (const float*)d_in[2];
    const float* b1 = (const float*)d_in[3];
    const float* W2 = (const float*)d_in[4];
    const float* b2 = (const float*)d_in[5];
    float* out = (float*)d_out;

    const int M = in_sizes[0] / 128;   // 100000 nodes
    const int E = in_sizes[1] / 2;     // 640000 edges

    u16* PQ = (u16*)d_ws;              // M*256*2 B = 51.2 MB

    int ntiles = (M + BM - 1) / BM;
    int gb = ntiles < 512 ? ntiles : 512;
    hipLaunchKernelGGL(node_gemm, dim3(gb), dim3(256), 0, stream,
                       z, W1, b1, PQ, M, ntiles);

    if (M < (1 << 17) && E < (1 << 20)) {
        int nch = (E + FCH - 1) / FCH;
        hipLaunchKernelGGL(edge_mlp_filter, dim3(nch * 8), dim3(256), 0, stream,
                           ei, PQ, W2, b2, out, E, M);
    } else {
        int eb = ((E + 3) / 4 * 16 + 255) / 256;
        hipLaunchKernelGGL(edge_mlp, dim3(eb), dim3(256), 0, stream,
                           ei, PQ, W2, b2, out, E);
    }
}

// Round 10
// 71.636 us; speedup vs baseline: 1.0825x; 1.0743x over previous
//
#include <hip/hip_runtime.h>
#include <hip/hip_bf16.h>

typedef short bf16x8 __attribute__((ext_vector_type(8)));
typedef float f32x4  __attribute__((ext_vector_type(4)));
typedef unsigned u32x4 __attribute__((ext_vector_type(4)));
typedef unsigned short u16;

// float -> bf16 round-to-nearest-even
static __device__ __forceinline__ u16 f2bf(float f) {
    unsigned u = __float_as_uint(f);
    u += 0x7FFFu + ((u >> 16) & 1u);
    return (u16)(u >> 16);
}
static __device__ __forceinline__ float bf2f(u16 b) {
    return __uint_as_float(((unsigned)b) << 16);
}
static __device__ __forceinline__ unsigned pack2(float lo, float hi) {
    return (unsigned)f2bf(lo) | ((unsigned)f2bf(hi) << 16);
}

// ---------------------------------------------------------------------------
// Persistent GEMM (R7-proven ~24us, no spill at (256,2)).
// PQ[m][c] = sum_k z[m][k]*W'[c][k] + b1[c] (c<128), where W'[c][k]=W1[k][c]
// (c<128) or W1[128+k][c-128]. bf16 out, fp32 accum.
// ---------------------------------------------------------------------------
#define BM 64
__global__ __launch_bounds__(256, 2) void node_gemm(
    const float* __restrict__ z,   // [M][128] fp32
    const float* __restrict__ W1,  // [256][128] fp32
    const float* __restrict__ b1,  // [128]
    u16*         __restrict__ PQ,  // [M][256] bf16
    int M, int ntiles)
{
    __shared__ char As[BM * 256];   // 16 KB: 64 rows x 128 bf16, swizzled
    __shared__ char Cb[BM * 512];   // 32 KB: 64 rows x 256 bf16, swizzled
    const int tid  = threadIdx.x;
    const int lane = tid & 63;
    const int wave = tid >> 6;
    const int g    = lane >> 4;     // k-group 0..3
    const int ln   = lane & 15;
    const int c0   = wave * 64;     // this wave's W'-column slice

    int t = blockIdx.x;
    if (t >= ntiles) return;

    // ---- tile-invariant: W' fragments (from W1 directly) and bias ----
    bf16x8 af[4][4];   // [ks][ci]
    #pragma unroll
    for (int ci = 0; ci < 4; ++ci) {
        int c = c0 + ci * 16 + ln;
        const float* src = (c < 128) ? (W1 + c) : (W1 + 128 * 128 + (c - 128));
        #pragma unroll
        for (int ks = 0; ks < 4; ++ks) {
            bf16x8 v;
            #pragma unroll
            for (int j = 0; j < 8; ++j)
                v[j] = (short)f2bf(src[(ks * 32 + g * 8 + j) * 128]);
            af[ks][ci] = v;
        }
    }

    float4 bias[4];
    #pragma unroll
    for (int ci = 0; ci < 4; ++ci) {
        int col = c0 + ci * 16 + g * 4;
        bias[ci] = (col < 128) ? *(const float4*)(b1 + col)
                               : make_float4(0.f, 0.f, 0.f, 0.f);
    }

    float4 r[8];       // z staging regs: 8 float4 chunks (64 rows x 32 ch)

    // ---- prologue: load + stage tile t ----
    {
        int m0 = t * BM;
        #pragma unroll
        for (int i = 0; i < 8; ++i) {
            int ci = tid + i * 256, row = ci >> 5, c4 = ci & 31;
            r[i] = make_float4(0.f, 0.f, 0.f, 0.f);
            if (m0 + row < M)
                r[i] = *(const float4*)(z + (size_t)(m0 + row) * 128 + c4 * 4);
        }
        #pragma unroll
        for (int i = 0; i < 8; ++i) {
            int ci = tid + i * 256, row = ci >> 5, c4 = ci & 31;
            ushort4 b;
            b.x = f2bf(r[i].x); b.y = f2bf(r[i].y);
            b.z = f2bf(r[i].z); b.w = f2bf(r[i].w);
            *(ushort4*)(As + row * 256 + ((c4 * 8) ^ ((row & 7) << 4))) = b;
        }
    }
    __syncthreads();

    while (true) {
        int next = t + gridDim.x;
        bool have = (next < ntiles);

        // ---- issue next tile's z loads (stay in flight through MFMA) ----
        if (have) {
            int m0 = next * BM;
            #pragma unroll
            for (int i = 0; i < 8; ++i) {
                int ci = tid + i * 256, row = ci >> 5, c4 = ci & 31;
                r[i] = make_float4(0.f, 0.f, 0.f, 0.f);
                if (m0 + row < M)
                    r[i] = *(const float4*)(z + (size_t)(m0 + row) * 128 + c4 * 4);
            }
        }

        // ---- MFMA tile t from As ----
        f32x4 acc[4][4];   // [mf][ci]
        #pragma unroll
        for (int mf = 0; mf < 4; ++mf)
            #pragma unroll
            for (int ci = 0; ci < 4; ++ci)
                acc[mf][ci] = (f32x4){0.f, 0.f, 0.f, 0.f};
        #pragma unroll
        for (int ks = 0; ks < 4; ++ks) {
            #pragma unroll
            for (int mf = 0; mf < 4; ++mf) {
                int row  = mf * 16 + ln;
                int byte = row * 256 + ((ks * 64 + g * 16) ^ ((row & 7) << 4));
                bf16x8 b = *(const bf16x8*)(As + byte);
                #pragma unroll
                for (int ci = 0; ci < 4; ++ci)
                    acc[mf][ci] = __builtin_amdgcn_mfma_f32_16x16x32_bf16(
                        af[ks][ci], b, acc[mf][ci], 0, 0, 0);
            }
        }

        // ---- pack acc (+bias) -> Cb, swizzled ----
        #pragma unroll
        for (int mf = 0; mf < 4; ++mf) {
            int node = mf * 16 + ln;
            #pragma unroll
            for (int ci = 0; ci < 4; ++ci) {
                int col = c0 + ci * 16 + g * 4;
                uint2 w;
                w.x = pack2(acc[mf][ci][0] + bias[ci].x,
                            acc[mf][ci][1] + bias[ci].y);
                w.y = pack2(acc[mf][ci][2] + bias[ci].z,
                            acc[mf][ci][3] + bias[ci].w);
                *(uint2*)(Cb + node * 512 + ((col * 2) ^ ((node & 7) << 4))) = w;
            }
        }
        __syncthreads();   // Cb complete; all waves done reading As

        // ---- coalesced C store: 512B contiguous per node row ----
        {
            int m0 = t * BM;
            int chunk = tid & 31;          // 16B chunk within 512B row
            int nb    = tid >> 5;
            #pragma unroll
            for (int it = 0; it < 8; ++it) {
                int node = it * 8 + nb;
                uint4 v = *(const uint4*)(Cb + node * 512 +
                                          ((chunk * 16) ^ ((node & 7) << 4)));
                if (m0 + node < M)
                    *(uint4*)(PQ + (size_t)(m0 + node) * 256 + chunk * 8) = v;
            }
        }

        // ---- stage next tile into As (waits only the z loads) ----
        if (have) {
            #pragma unroll
            for (int i = 0; i < 8; ++i) {
                int ci = tid + i * 256, row = ci >> 5, c4 = ci & 31;
                ushort4 b;
                b.x = f2bf(r[i].x); b.y = f2bf(r[i].y);
                b.z = f2bf(r[i].z); b.w = f2bf(r[i].w);
                *(ushort4*)(As + row * 256 + ((c4 * 8) ^ ((row & 7) << 4))) = b;
            }
        } else {
            break;
        }
        __syncthreads();   // As staged, Cb readback done, before next pack
        t = next;
    }
}

// ---------------------------------------------------------------------------
// Edge kernel: out[e] = relu(P[s] + Q[d]) . W2 + b2  (b1 pre-folded into P).
// 16 lanes x 4 edges per thread. Q-side gathers are NON-TEMPORAL: Q lines are
// effectively streaming (reuse ~6.4 spread over the whole kernel), so keeping
// them out of L2 leaves ~2x capacity for P lines -> higher P hit rate.
// Bound by random-gather L3 service (~3.2 TB/s) on the miss traffic.
// ---------------------------------------------------------------------------
__global__ __launch_bounds__(256) void edge_mlp(
    const int* __restrict__ ei,    // [2][E] int32
    const u16* __restrict__ PQ,    // [M][256] bf16 (P = first 128, Q = last)
    const float* __restrict__ W2,  // [128]
    const float* __restrict__ b2,  // [1]
    float* __restrict__ out,       // [E]
    int E)
{
    int gid = blockIdx.x * 256 + threadIdx.x;
    int e0  = (gid >> 4) * 4;
    int sub = gid & 15;
    if (e0 >= E) return;

    float4 w2a = *(const float4*)(W2 + sub * 8);
    float4 w2b = *(const float4*)(W2 + sub * 8 + 4);
    float ww[8] = {w2a.x, w2a.y, w2a.z, w2a.w, w2b.x, w2b.y, w2b.z, w2b.w};
    float bias = b2[0];

    if (e0 + 3 < E) {
        int4 s = *(const int4*)(ei + e0);
        int4 d = *(const int4*)(ei + E + e0);
        u32x4 p0 = *(const u32x4*)(PQ + (size_t)s.x * 256 + sub * 8);
        u32x4 p1 = *(const u32x4*)(PQ + (size_t)s.y * 256 + sub * 8);
        u32x4 p2 = *(const u32x4*)(PQ + (size_t)s.z * 256 + sub * 8);
        u32x4 p3 = *(const u32x4*)(PQ + (size_t)s.w * 256 + sub * 8);
        u32x4 q0 = __builtin_nontemporal_load(
                       (const u32x4*)(PQ + (size_t)d.x * 256 + 128 + sub * 8));
        u32x4 q1 = __builtin_nontemporal_load(
                       (const u32x4*)(PQ + (size_t)d.y * 256 + 128 + sub * 8));
        u32x4 q2 = __builtin_nontemporal_load(
                       (const u32x4*)(PQ + (size_t)d.z * 256 + 128 + sub * 8));
        u32x4 q3 = __builtin_nontemporal_load(
                       (const u32x4*)(PQ + (size_t)d.w * 256 + 128 + sub * 8));

        float a0 = 0.f, a1 = 0.f, a2 = 0.f, a3 = 0.f;
        const u16* pu0 = (const u16*)&p0; const u16* qu0 = (const u16*)&q0;
        const u16* pu1 = (const u16*)&p1; const u16* qu1 = (const u16*)&q1;
        const u16* pu2 = (const u16*)&p2; const u16* qu2 = (const u16*)&q2;
        const u16* pu3 = (const u16*)&p3; const u16* qu3 = (const u16*)&q3;
        #pragma unroll
        for (int j = 0; j < 8; ++j) {
            a0 = fmaf(fmaxf(bf2f(pu0[j]) + bf2f(qu0[j]), 0.f), ww[j], a0);
            a1 = fmaf(fmaxf(bf2f(pu1[j]) + bf2f(qu1[j]), 0.f), ww[j], a1);
            a2 = fmaf(fmaxf(bf2f(pu2[j]) + bf2f(qu2[j]), 0.f), ww[j], a2);
            a3 = fmaf(fmaxf(bf2f(pu3[j]) + bf2f(qu3[j]), 0.f), ww[j], a3);
        }
        #pragma unroll
        for (int m = 1; m < 16; m <<= 1) {
            a0 += __shfl_xor(a0, m);
            a1 += __shfl_xor(a1, m);
            a2 += __shfl_xor(a2, m);
            a3 += __shfl_xor(a3, m);
        }
        if (sub == 0) {
            float4 o = make_float4(a0 + bias, a1 + bias, a2 + bias, a3 + bias);
            *(float4*)(out + e0) = o;
        }
    } else {
        for (int k = 0; k < 4; ++k) {
            int e = e0 + k;
            if (e >= E) break;
            int sn = ei[e], dn = ei[E + e];
            u32x4 p = *(const u32x4*)(PQ + (size_t)sn * 256 + sub * 8);
            u32x4 q = __builtin_nontemporal_load(
                          (const u32x4*)(PQ + (size_t)dn * 256 + 128 + sub * 8));
            const u16* pu = (const u16*)&p; const u16* qu = (const u16*)&q;
            float acc = 0.f;
            #pragma unroll
            for (int j = 0; j < 8; ++j)
                acc = fmaf(fmaxf(bf2f(pu[j]) + bf2f(qu[j]), 0.f), ww[j], acc);
            #pragma unroll
            for (int m = 1; m < 16; m <<= 1) acc += __shfl_xor(acc, m);
            if (sub == 0) out[e] = acc + bias;
        }
    }
}

// ---------------------------------------------------------------------------
extern "C" void kernel_launch(void* const* d_in, const int* in_sizes, int n_in,
                              void* d_out, int out_size, void* d_ws, size_t ws_size,
                              hipStream_t stream) {
    const float* z  = (const float*)d_in[0];
    const int*   ei = (const int*)d_in[1];
    const float* W1 = (const float*)d_in[2];
    const float* b1 = (const float*)d_in[3];
    const float* W2 = (const float*)d_in[4];
    const float* b2 = (const float*)d_in[5];
    float* out = (float*)d_out;

    const int M = in_sizes[0] / 128;   // 100000 nodes
    const int E = in_sizes[1] / 2;     // 640000 edges

    u16* PQ = (u16*)d_ws;              // M*256*2 B = 51.2 MB

    int ntiles = (M + BM - 1) / BM;
    int gb = ntiles < 512 ? ntiles : 512;
    hipLaunchKernelGGL(node_gemm, dim3(gb), dim3(256), 0, stream,
                       z, W1, b1, PQ, M, ntiles);

    int eb = ((E + 3) / 4 * 16 + 255) / 256;
    hipLaunchKernelGGL(edge_mlp, dim3(eb), dim3(256), 0, stream,
                       ei, PQ, W2, b2, out, E);
}

// Round 13
// 71.309 us; speedup vs baseline: 1.0875x; 1.0046x over previous
//
#include <hip/hip_runtime.h>
#include <hip/hip_bf16.h>

typedef short bf16x8 __attribute__((ext_vector_type(8)));
typedef float f32x4  __attribute__((ext_vector_type(4)));
typedef unsigned u32x4 __attribute__((ext_vector_type(4)));
typedef unsigned short u16;

// float -> bf16 round-to-nearest-even
static __device__ __forceinline__ u16 f2bf(float f) {
    unsigned u = __float_as_uint(f);
    u += 0x7FFFu + ((u >> 16) & 1u);
    return (u16)(u >> 16);
}
static __device__ __forceinline__ float bf2f(u16 b) {
    return __uint_as_float(((unsigned)b) << 16);
}
static __device__ __forceinline__ unsigned pack2(float lo, float hi) {
    return (unsigned)f2bf(lo) | ((unsigned)f2bf(hi) << 16);
}

// ---------------------------------------------------------------------------
// Persistent GEMM (R7/R10-proven ~24us, no spill at (256,2)).
// PQ[m][c] = sum_k z[m][k]*W'[c][k] + b1[c] (c<128), where W'[c][k]=W1[k][c]
// (c<128) or W1[128+k][c-128]. bf16 out, fp32 accum.
// ---------------------------------------------------------------------------
#define BM 64
__global__ __launch_bounds__(256, 2) void node_gemm(
    const float* __restrict__ z,   // [M][128] fp32
    const float* __restrict__ W1,  // [256][128] fp32
    const float* __restrict__ b1,  // [128]
    u16*         __restrict__ PQ,  // [M][256] bf16
    int M, int ntiles)
{
    __shared__ char As[BM * 256];   // 16 KB: 64 rows x 128 bf16, swizzled
    __shared__ char Cb[BM * 512];   // 32 KB: 64 rows x 256 bf16, swizzled
    const int tid  = threadIdx.x;
    const int lane = tid & 63;
    const int wave = tid >> 6;
    const int g    = lane >> 4;     // k-group 0..3
    const int ln   = lane & 15;
    const int c0   = wave * 64;     // this wave's W'-column slice

    int t = blockIdx.x;
    if (t >= ntiles) return;

    // ---- tile-invariant: W' fragments (from W1 directly) and bias ----
    bf16x8 af[4][4];   // [ks][ci]
    #pragma unroll
    for (int ci = 0; ci < 4; ++ci) {
        int c = c0 + ci * 16 + ln;
        const float* src = (c < 128) ? (W1 + c) : (W1 + 128 * 128 + (c - 128));
        #pragma unroll
        for (int ks = 0; ks < 4; ++ks) {
            bf16x8 v;
            #pragma unroll
            for (int j = 0; j < 8; ++j)
                v[j] = (short)f2bf(src[(ks * 32 + g * 8 + j) * 128]);
            af[ks][ci] = v;
        }
    }

    float4 bias[4];
    #pragma unroll
    for (int ci = 0; ci < 4; ++ci) {
        int col = c0 + ci * 16 + g * 4;
        bias[ci] = (col < 128) ? *(const float4*)(b1 + col)
                               : make_float4(0.f, 0.f, 0.f, 0.f);
    }

    float4 r[8];       // z staging regs: 8 float4 chunks (64 rows x 32 ch)

    // ---- prologue: load + stage tile t ----
    {
        int m0 = t * BM;
        #pragma unroll
        for (int i = 0; i < 8; ++i) {
            int ci = tid + i * 256, row = ci >> 5, c4 = ci & 31;
            r[i] = make_float4(0.f, 0.f, 0.f, 0.f);
            if (m0 + row < M)
                r[i] = *(const float4*)(z + (size_t)(m0 + row) * 128 + c4 * 4);
        }
        #pragma unroll
        for (int i = 0; i < 8; ++i) {
            int ci = tid + i * 256, row = ci >> 5, c4 = ci & 31;
            ushort4 b;
            b.x = f2bf(r[i].x); b.y = f2bf(r[i].y);
            b.z = f2bf(r[i].z); b.w = f2bf(r[i].w);
            *(ushort4*)(As + row * 256 + ((c4 * 8) ^ ((row & 7) << 4))) = b;
        }
    }
    __syncthreads();

    while (true) {
        int next = t + gridDim.x;
        bool have = (next < ntiles);

        // ---- issue next tile's z loads (stay in flight through MFMA) ----
        if (have) {
            int m0 = next * BM;
            #pragma unroll
            for (int i = 0; i < 8; ++i) {
                int ci = tid + i * 256, row = ci >> 5, c4 = ci & 31;
                r[i] = make_float4(0.f, 0.f, 0.f, 0.f);
                if (m0 + row < M)
                    r[i] = *(const float4*)(z + (size_t)(m0 + row) * 128 + c4 * 4);
            }
        }

        // ---- MFMA tile t from As ----
        f32x4 acc[4][4];   // [mf][ci]
        #pragma unroll
        for (int mf = 0; mf < 4; ++mf)
            #pragma unroll
            for (int ci = 0; ci < 4; ++ci)
                acc[mf][ci] = (f32x4){0.f, 0.f, 0.f, 0.f};
        #pragma unroll
        for (int ks = 0; ks < 4; ++ks) {
            #pragma unroll
            for (int mf = 0; mf < 4; ++mf) {
                int row  = mf * 16 + ln;
                int byte = row * 256 + ((ks * 64 + g * 16) ^ ((row & 7) << 4));
                bf16x8 b = *(const bf16x8*)(As + byte);
                #pragma unroll
                for (int ci = 0; ci < 4; ++ci)
                    acc[mf][ci] = __builtin_amdgcn_mfma_f32_16x16x32_bf16(
                        af[ks][ci], b, acc[mf][ci], 0, 0, 0);
            }
        }

        // ---- pack acc (+bias) -> Cb, swizzled ----
        #pragma unroll
        for (int mf = 0; mf < 4; ++mf) {
            int node = mf * 16 + ln;
            #pragma unroll
            for (int ci = 0; ci < 4; ++ci) {
                int col = c0 + ci * 16 + g * 4;
                uint2 w;
                w.x = pack2(acc[mf][ci][0] + bias[ci].x,
                            acc[mf][ci][1] + bias[ci].y);
                w.y = pack2(acc[mf][ci][2] + bias[ci].z,
                            acc[mf][ci][3] + bias[ci].w);
                *(uint2*)(Cb + node * 512 + ((col * 2) ^ ((node & 7) << 4))) = w;
            }
        }
        __syncthreads();   // Cb complete; all waves done reading As

        // ---- coalesced C store: 512B contiguous per node row ----
        {
            int m0 = t * BM;
            int chunk = tid & 31;          // 16B chunk within 512B row
            int nb    = tid >> 5;
            #pragma unroll
            for (int it = 0; it < 8; ++it) {
                int node = it * 8 + nb;
                uint4 v = *(const uint4*)(Cb + node * 512 +
                                          ((chunk * 16) ^ ((node & 7) << 4)));
                if (m0 + node < M)
                    *(uint4*)(PQ + (size_t)(m0 + node) * 256 + chunk * 8) = v;
            }
        }

        // ---- stage next tile into As (waits only the z loads) ----
        if (have) {
            #pragma unroll
            for (int i = 0; i < 8; ++i) {
                int ci = tid + i * 256, row = ci >> 5, c4 = ci & 31;
                ushort4 b;
                b.x = f2bf(r[i].x); b.y = f2bf(r[i].y);
                b.z = f2bf(r[i].z); b.w = f2bf(r[i].w);
                *(ushort4*)(As + row * 256 + ((c4 * 8) ^ ((row & 7) << 4))) = b;
            }
        } else {
            break;
        }
        __syncthreads();   // As staged, Cb readback done, before next pack
        t = next;
    }
}

// ---------------------------------------------------------------------------
// Edge kernel: out[e] = relu(P[s] + Q[d]) . W2 + b2  (b1 pre-folded into P).
// 16 lanes x 4 edges per thread. Bound by the L2-miss random-gather service
// path (~3.2 TB/s): 328 MB of random 256B row requests over a 51 MB working
// set, ~150 MB L2 misses. Dur is identical at 150 MB (cold) and 2.5 MB
// (L3-warm) FETCH -> not HBM-bound. Sort/partition/filter variants all
// failed to beat it (R8/R9/R11/R12): the Q side is irreducibly random.
// ---------------------------------------------------------------------------
__global__ __launch_bounds__(256) void edge_mlp(
    const int* __restrict__ ei,    // [2][E] int32
    const u16* __restrict__ PQ,    // [M][256] bf16 (P = first 128, Q = last)
    const float* __restrict__ W2,  // [128]
    const float* __restrict__ b2,  // [1]
    float* __restrict__ out,       // [E]
    int E)
{
    int gid = blockIdx.x * 256 + threadIdx.x;
    int e0  = (gid >> 4) * 4;
    int sub = gid & 15;
    if (e0 >= E) return;

    float4 w2a = *(const float4*)(W2 + sub * 8);
    float4 w2b = *(const float4*)(W2 + sub * 8 + 4);
    float ww[8] = {w2a.x, w2a.y, w2a.z, w2a.w, w2b.x, w2b.y, w2b.z, w2b.w};
    float bias = b2[0];

    if (e0 + 3 < E) {
        int4 s = *(const int4*)(ei + e0);
        int4 d = *(const int4*)(ei + E + e0);
        u32x4 p0 = *(const u32x4*)(PQ + (size_t)s.x * 256 + sub * 8);
        u32x4 p1 = *(const u32x4*)(PQ + (size_t)s.y * 256 + sub * 8);
        u32x4 p2 = *(const u32x4*)(PQ + (size_t)s.z * 256 + sub * 8);
        u32x4 p3 = *(const u32x4*)(PQ + (size_t)s.w * 256 + sub * 8);
        u32x4 q0 = __builtin_nontemporal_load(
                       (const u32x4*)(PQ + (size_t)d.x * 256 + 128 + sub * 8));
        u32x4 q1 = __builtin_nontemporal_load(
                       (const u32x4*)(PQ + (size_t)d.y * 256 + 128 + sub * 8));
        u32x4 q2 = __builtin_nontemporal_load(
                       (const u32x4*)(PQ + (size_t)d.z * 256 + 128 + sub * 8));
        u32x4 q3 = __builtin_nontemporal_load(
                       (const u32x4*)(PQ + (size_t)d.w * 256 + 128 + sub * 8));

        float a0 = 0.f, a1 = 0.f, a2 = 0.f, a3 = 0.f;
        const u16* pu0 = (const u16*)&p0; const u16* qu0 = (const u16*)&q0;
        const u16* pu1 = (const u16*)&p1; const u16* qu1 = (const u16*)&q1;
        const u16* pu2 = (const u16*)&p2; const u16* qu2 = (const u16*)&q2;
        const u16* pu3 = (const u16*)&p3; const u16* qu3 = (const u16*)&q3;
        #pragma unroll
        for (int j = 0; j < 8; ++j) {
            a0 = fmaf(fmaxf(bf2f(pu0[j]) + bf2f(qu0[j]), 0.f), ww[j], a0);
            a1 = fmaf(fmaxf(bf2f(pu1[j]) + bf2f(qu1[j]), 0.f), ww[j], a1);
            a2 = fmaf(fmaxf(bf2f(pu2[j]) + bf2f(qu2[j]), 0.f), ww[j], a2);
            a3 = fmaf(fmaxf(bf2f(pu3[j]) + bf2f(qu3[j]), 0.f), ww[j], a3);
        }
        #pragma unroll
        for (int m = 1; m < 16; m <<= 1) {
            a0 += __shfl_xor(a0, m);
            a1 += __shfl_xor(a1, m);
            a2 += __shfl_xor(a2, m);
            a3 += __shfl_xor(a3, m);
        }
        if (sub == 0) {
            float4 o = make_float4(a0 + bias, a1 + bias, a2 + bias, a3 + bias);
            *(float4*)(out + e0) = o;
        }
    } else {
        for (int k = 0; k < 4; ++k) {
            int e = e0 + k;
            if (e >= E) break;
            int sn = ei[e], dn = ei[E + e];
            u32x4 p = *(const u32x4*)(PQ + (size_t)sn * 256 + sub * 8);
            u32x4 q = __builtin_nontemporal_load(
                          (const u32x4*)(PQ + (size_t)dn * 256 + 128 + sub * 8));
            const u16* pu = (const u16*)&p; const u16* qu = (const u16*)&q;
            float acc = 0.f;
            #pragma unroll
            for (int j = 0; j < 8; ++j)
                acc = fmaf(fmaxf(bf2f(pu[j]) + bf2f(qu[j]), 0.f), ww[j], acc);
            #pragma unroll
            for (int m = 1; m < 16; m <<= 1) acc += __shfl_xor(acc, m);
            if (sub == 0) out[e] = acc + bias;
        }
    }
}

// ---------------------------------------------------------------------------
extern "C" void kernel_launch(void* const* d_in, const int* in_sizes, int n_in,
                              void* d_out, int out_size, void* d_ws, size_t ws_size,
                              hipStream_t stream) {
    const float* z  = (const float*)d_in[0];
    const int*   ei = (const int*)d_in[1];
    const float* W1 = (const float*)d_in[2];
    const float* b1 = (const float*)d_in[3];
    const float* W2 = (const float*)d_in[4];
    const float* b2 = (const float*)d_in[5];
    float* out = (float*)d_out;

    const int M = in_sizes[0] / 128;   // 100000 nodes
    const int E = in_sizes[1] / 2;     // 640000 edges

    u16* PQ = (u16*)d_ws;              // M*256*2 B = 51.2 MB

    int ntiles = (M + BM - 1) / BM;
    int gb = ntiles < 512 ? ntiles : 512;
    hipLaunchKernelGGL(node_gemm, dim3(gb), dim3(256), 0, stream,
                       z, W1, b1, PQ, M, ntiles);

    int eb = ((E + 3) / 4 * 16 + 255) / 256;
    hipLaunchKernelGGL(edge_mlp, dim3(eb), dim3(256), 0, stream,
                       ei, PQ, W2, b2, out, E);
}